// Round 10
// baseline (247.149 us; speedup 1.0000x reference)
//
#include <hip/hip_runtime.h>
#include <hip/hip_bf16.h>

typedef __attribute__((ext_vector_type(8))) short short8;   // 8 bf16 = 4 VGPRs
typedef __attribute__((ext_vector_type(4))) float float4v;  // 4 fp32 acc
typedef __attribute__((ext_vector_type(2))) unsigned int uint2v;
typedef __hip_bfloat16 bf16;

#define MFMA16(a, b, c) __builtin_amdgcn_mfma_f32_16x16x32_bf16((a), (b), (c), 0, 0, 0)

static __device__ __forceinline__ short8 load8(const bf16* p) {
    return *reinterpret_cast<const short8*>(p);
}
static __device__ __forceinline__ unsigned short bfu(float x) {
    union { bf16 b; unsigned short u; } c; c.b = __float2bfloat16(x); return c.u;
}
static __device__ __forceinline__ unsigned pack2(float lo, float hi) {
    return ((unsigned)bfu(hi) << 16) | bfu(lo);
}
static __device__ __forceinline__ short bf_bits(float x) {
    union { bf16 b; short u; } c; c.b = __float2bfloat16(x); return c.u;
}
static __device__ __forceinline__ short8 cvt8(float4 a, float4 b) {
    short8 r;
    r[0] = bf_bits(a.x); r[1] = bf_bits(a.y); r[2] = bf_bits(a.z); r[3] = bf_bits(a.w);
    r[4] = bf_bits(b.x); r[5] = bf_bits(b.y); r[6] = bf_bits(b.z); r[7] = bf_bits(b.w);
    return r;
}

// async global -> LDS, 16B per lane. LDS dest = wave-uniform base + lane*16.
typedef const __attribute__((address_space(1))) unsigned int* gp1;
typedef __attribute__((address_space(3))) unsigned int* lp3;
static __device__ __forceinline__ void async16(const void* g, void* l) {
    __builtin_amdgcn_global_load_lds((gp1)g, (lp3)l, 16, 0, 0);
}

// ---------------------------------------------------------------------------
// QKV projection GEMM — v7: in-kernel W transpose (transpose_qkv kernel
// eliminated; 5->3 launches total). B tile Wz^T[n][k] is built per-iter from
// coalesced fp32 row reads of Wz[k][n]: each lane loads 16 cols of rows
// (k0,k0+1), cvt+pack to bf16 pairs, ds_write_b32 into the SAME swizzled Bs
// layout as before (slot ^= n&7) -> fragment reads and numerics unchanged
// (identical __float2bfloat16). ~8-way write conflicts on 16 b32 writes
// accepted (LDS pipe ~50% busy). A staging (fp32 async16) unchanged.
// BK=64, single-buffered, 16 iters, 32 MFMA/barrier-pair, XCD swizzle.
// Q output pre-scaled by log2(e)/8 (folds attn score scale into projection).
// ---------------------------------------------------------------------------
__global__ __launch_bounds__(256, 3) void qkv_gemm(
    const float* __restrict__ Xq, const float* __restrict__ Xk,
    const float* __restrict__ Xv,
    const float* __restrict__ Wq, const float* __restrict__ Wk,
    const float* __restrict__ Wv,
    const float* __restrict__ bq, const float* __restrict__ bk,
    const float* __restrict__ bv,
    bf16* __restrict__ outq, bf16* __restrict__ outk, bf16* __restrict__ outv)
{
    __shared__ float As[128 * 64];   // 32KB
    __shared__ bf16  Bs[128 * 64];   // 16KB  [n][k] transposed W

    int wg = blockIdx.x;
    int xcd = wg & 7;
    int jj = wg >> 3;                  // 0..95
    int grp = xcd * 12 + (jj >> 3);    // 0..95
    int z = grp >> 5;                  // 0..2
    int m_blk = grp & 31;
    int n_blk = jj & 7;

    const float* X    = (z == 0) ? Xq : (z == 1) ? Xk : Xv;
    const float* W    = (z == 0) ? Wq : (z == 1) ? Wk : Wv;
    const float* bias = (z == 0) ? bq : (z == 1) ? bk : bv;
    bf16*        out  = (z == 0) ? outq : (z == 1) ? outk : outv;
    bool vmode = (z == 2);

    int tid = threadIdx.x;
    int w = tid >> 6, lane = tid & 63, l16 = lane & 15, quad = lane >> 4;
    int m_base = m_blk * 128, n_base = n_blk * 128;

    // A staging lane constants (4 rows x 16 slots of 16B per async16)
    int r4 = lane >> 4, s16 = lane & 15;
    const float* Asrc0 = X + (size_t)(m_base + w * 32 + r4) * 1024 + ((s16 ^ r4) << 2);
    const float* Asrc1 = X + (size_t)(m_base + w * 32 + r4) * 1024 + ((s16 ^ (4 + r4)) << 2);

    // B transpose-staging lane constants: wave w covers k-rows w*16..w*16+15
    // as 8 pairs; lane = pair bp (lane>>3) x n-group bli (lane&7).
    int bp  = lane >> 3;               // 0..7  -> rows k0 = w*16 + bp*2, +1
    int bli = lane & 7;                // 0..7  -> n = n_base + bli*16 + i
    const float* Wsrc = W + (size_t)(w * 16 + bp * 2) * 1024 + n_base + bli * 16;
    int bslot = w * 2 + (bp >> 2);     // 16B-slot index of k-pair
    int bwk   = (bp & 3) * 4;          // byte offset within slot
    char* bbase = (char*)Bs + bli * 2048 + bwk;

    int wm = (w & 1) * 64, wn = (w >> 1) * 64;
    int sw = l16 & 7;

    float4v zero = {0.f, 0.f, 0.f, 0.f};
    float4v acc[4][4];
    #pragma unroll
    for (int mi = 0; mi < 4; ++mi)
        #pragma unroll
        for (int nj = 0; nj < 4; ++nj) acc[mi][nj] = zero;

    for (int it = 0; it < 16; ++it) {
        int kt = it * 64;
        // A: async16 -> LDS (unchanged)
        #pragma unroll
        for (int p = 0; p < 8; ++p) {
            const float* s = ((p & 1) ? Asrc1 : Asrc0) + (size_t)p * 4096 + kt;
            async16(s, (char*)As + (w * 32 + p * 4) * 256);
        }
        // B: load W rows fp32 -> cvt -> transposed swizzled ds_write
        {
            const float* r0 = Wsrc + (size_t)kt * 1024;
            const float* r1 = r0 + 1024;
            float fa[16], fb[16];
            *(float4*)(fa + 0)  = *(const float4*)(r0 + 0);
            *(float4*)(fa + 4)  = *(const float4*)(r0 + 4);
            *(float4*)(fa + 8)  = *(const float4*)(r0 + 8);
            *(float4*)(fa + 12) = *(const float4*)(r0 + 12);
            *(float4*)(fb + 0)  = *(const float4*)(r1 + 0);
            *(float4*)(fb + 4)  = *(const float4*)(r1 + 4);
            *(float4*)(fb + 8)  = *(const float4*)(r1 + 8);
            *(float4*)(fb + 12) = *(const float4*)(r1 + 12);
            #pragma unroll
            for (int i = 0; i < 16; ++i)
                *(unsigned*)(bbase + i * 128 + ((bslot ^ (i & 7)) << 4)) =
                    pack2(fa[i], fb[i]);
        }
        __syncthreads();

        #pragma unroll
        for (int kk = 0; kk < 2; ++kk) {
            short8 af[4], bfr[4];
            #pragma unroll
            for (int mi = 0; mi < 4; ++mi) {
                const float* rp = As + (wm + mi * 16 + l16) * 64;
                float4 f0 = *(const float4*)(rp + (((kk * 8 + quad * 2)     ^ sw) << 2));
                float4 f1 = *(const float4*)(rp + (((kk * 8 + quad * 2 + 1) ^ sw) << 2));
                af[mi] = cvt8(f0, f1);
            }
            #pragma unroll
            for (int nj = 0; nj < 4; ++nj) {
                const bf16* rp = Bs + (wn + nj * 16 + l16) * 64;
                bfr[nj] = load8(rp + (((kk * 4 + quad) ^ sw) << 3));
            }
            #pragma unroll
            for (int mi = 0; mi < 4; ++mi)
                #pragma unroll
                for (int nj = 0; nj < 4; ++nj)
                    acc[mi][nj] = MFMA16(af[mi], bfr[nj], acc[mi][nj]);
        }
        __syncthreads();
    }

    float bsv[4];
    #pragma unroll
    for (int nj = 0; nj < 4; ++nj)
        bsv[nj] = bias[n_base + wn + nj * 16 + l16];

    // fold attention scale into q: C = log2(e)/8
    float qs = (z == 0) ? 0.18033688f : 1.0f;

    #pragma unroll
    for (int mi = 0; mi < 4; ++mi) {
        #pragma unroll
        for (int nj = 0; nj < 4; ++nj) {
            int n = n_base + wn + nj * 16 + l16;
            int h = n >> 6, dk = n & 63;
            int m0 = m_base + wm + mi * 16 + quad * 4;
            int b = m0 >> 11, s0 = m0 & 2047;
            if (vmode) {
                float v0 = acc[mi][nj][0] + bsv[nj];
                float v1 = acc[mi][nj][1] + bsv[nj];
                float v2 = acc[mi][nj][2] + bsv[nj];
                float v3 = acc[mi][nj][3] + bsv[nj];
                uint2 pv; pv.x = pack2(v0, v1); pv.y = pack2(v2, v3);
                size_t idx = ((size_t)(b * 16 + h) * 64 + dk) * 2048 + s0;
                *reinterpret_cast<uint2*>(out + idx) = pv;
            } else {
                #pragma unroll
                for (int r = 0; r < 4; ++r) {
                    size_t idx = (((size_t)(b * 16 + h) * 2048 + s0 + r) * 64 + dk);
                    out[idx] = __float2bfloat16((acc[mi][nj][r] + bsv[nj]) * qs);
                }
            }
        }
    }
}

// ---------------------------------------------------------------------------
// Output projection: out[4096,1024] fp32 = A(bf16) @ Wo + bo.
// v7: in-kernel Wo transpose (transpose_one eliminated). B tile Wo^T[n][k]
// built per-iter from coalesced fp32 row reads of Wo[k][n] (same pattern as
// qkv v7; ~4-way write conflicts). A staging (aout bf16 async16) unchanged;
// fragment reads unchanged -> bit-identical numerics. BK=128, 8 iters,
// 32 MFMA per barrier-pair. Tile 128x64, grid 512, XCD swizzle.
// ---------------------------------------------------------------------------
__global__ __launch_bounds__(256, 2) void out_gemm(
    const bf16* __restrict__ A, const float* __restrict__ Wo,
    const float* __restrict__ bias, float* __restrict__ out)
{
    __shared__ bf16 As[128 * 128];   // 32KB
    __shared__ bf16 Bs[64 * 128];    // 16KB  [n][k] transposed Wo

    int wg = blockIdx.x;
    int xcd = wg & 7;
    int jj = wg >> 3;                  // 0..63
    int m_blk = xcd * 4 + (jj >> 4);   // 0..31
    int n_blk = jj & 15;

    int tid = threadIdx.x;
    int w = tid >> 6, lane = tid & 63, l16 = lane & 15, quad = lane >> 4;
    int m_base = m_blk * 128, n_base = n_blk * 64;

    // A staging lane constants: each async16 covers 4 rows x 16 slots of 16B
    int r4 = lane >> 4, s16 = lane & 15;

    // B transpose-staging: wave w covers k-rows w*32..w*32+31 as 16 pairs;
    // lane = pair bp (lane>>2) x n-group bli (lane&3).
    int bp  = lane >> 2;               // 0..15 -> rows k0 = w*32 + bp*2, +1
    int bli = lane & 3;                // 0..3  -> n = n_base + bli*16 + i
    const float* Wsrc = Wo + (size_t)(w * 32 + bp * 2) * 1024 + n_base + bli * 16;
    int bslot = w * 4 + (bp >> 2);     // 16B-slot index of k-pair (0..15)
    int bwk   = (bp & 3) * 4;
    char* bbase = (char*)Bs + bli * 4096 + bwk;

    int wm = (w & 1) * 64, wn = (w >> 1) * 32;

    float4v zero = {0.f, 0.f, 0.f, 0.f};
    float4v acc[4][2];
    #pragma unroll
    for (int mi = 0; mi < 4; ++mi)
        #pragma unroll
        for (int nj = 0; nj < 2; ++nj) acc[mi][nj] = zero;

    for (int it = 0; it < 8; ++it) {
        int kt = it * 128;
        // A: wave w stages rows w*32 .. w*32+31 (8 async16 of 4 rows)
        #pragma unroll
        for (int p = 0; p < 8; ++p) {
            int row = w * 32 + p * 4 + r4;
            const bf16* s = A + (size_t)(m_base + row) * 1024 + kt
                              + ((s16 ^ (row & 15)) << 3);
            async16(s, (char*)As + (w * 32 + p * 4) * 256);
        }
        // B: load Wo rows fp32 -> cvt -> transposed swizzled ds_write
        {
            const float* r0 = Wsrc + (size_t)kt * 1024;
            const float* r1 = r0 + 1024;
            float fa[16], fb[16];
            *(float4*)(fa + 0)  = *(const float4*)(r0 + 0);
            *(float4*)(fa + 4)  = *(const float4*)(r0 + 4);
            *(float4*)(fa + 8)  = *(const float4*)(r0 + 8);
            *(float4*)(fa + 12) = *(const float4*)(r0 + 12);
            *(float4*)(fb + 0)  = *(const float4*)(r1 + 0);
            *(float4*)(fb + 4)  = *(const float4*)(r1 + 4);
            *(float4*)(fb + 8)  = *(const float4*)(r1 + 8);
            *(float4*)(fb + 12) = *(const float4*)(r1 + 12);
            #pragma unroll
            for (int i = 0; i < 16; ++i)
                *(unsigned*)(bbase + i * 256 + ((bslot ^ i) << 4)) =
                    pack2(fa[i], fb[i]);
        }
        __syncthreads();

        #pragma unroll
        for (int kk = 0; kk < 4; ++kk) {
            short8 af[4], bfr[2];
            #pragma unroll
            for (int mi = 0; mi < 4; ++mi) {
                const bf16* rp = As + (wm + mi * 16 + l16) * 128;
                af[mi] = load8(rp + (((kk * 4 + quad) ^ l16) << 3));
            }
            #pragma unroll
            for (int nj = 0; nj < 2; ++nj) {
                const bf16* rp = Bs + (wn + nj * 16 + l16) * 128;
                bfr[nj] = load8(rp + (((kk * 4 + quad) ^ l16) << 3));
            }
            #pragma unroll
            for (int mi = 0; mi < 4; ++mi)
                #pragma unroll
                for (int nj = 0; nj < 2; ++nj)
                    acc[mi][nj] = MFMA16(af[mi], bfr[nj], acc[mi][nj]);
        }
        __syncthreads();
    }

    float bsv[2];
    #pragma unroll
    for (int nj = 0; nj < 2; ++nj)
        bsv[nj] = bias[n_base + wn + nj * 16 + l16];

    #pragma unroll
    for (int mi = 0; mi < 4; ++mi)
        #pragma unroll
        for (int nj = 0; nj < 2; ++nj) {
            int n = n_base + wn + nj * 16 + l16;
            int m0 = m_base + wm + mi * 16 + quad * 4;
            #pragma unroll
            for (int r = 0; r < 4; ++r)
                out[(size_t)(m0 + r) * 1024 + n] = acc[mi][nj][r] + bsv[nj];
        }
}

// ---------------------------------------------------------------------------
// Flash attention, S-transposed. v6b (kept; attn plateau ~60us across five
// structural variants): 8 waves x 1 q-tile, grid 512, 3-deep K/V pipeline
// with counted vmcnt + sched_barrier(0) hardening, in-register P via
// permlane swaps, Q pre-scaled by log2(e)/8.
// LDS: 3x8K + 3x8K + maskb = 48.3KB; 2 blocks/CU.
// ---------------------------------------------------------------------------
__global__ __launch_bounds__(512, 4) void attn_fused(
    const bf16* __restrict__ Qm, const bf16* __restrict__ Km,
    const bf16* __restrict__ Vt, const int* __restrict__ mask,
    bf16* __restrict__ Oout)
{
    __shared__ __align__(16) bf16 Kc[3][64 * 64];  // 3 x 8KB [key][d]
    __shared__ __align__(16) bf16 Vc[3][64 * 64];  // 3 x 8KB [d][key]
    __shared__ unsigned long long maskb[32];       // bit k of [c] = mask[c*64+k]

    int tid = threadIdx.x;
    int w = tid >> 6, lane = tid & 63, l16 = lane & 15, quad = lane >> 4;
    int wg = blockIdx.x;
    int xcd = wg & 7;
    int jj = wg >> 3;                  // 0..63
    int bh = xcd * 4 + (jj >> 4);      // 0..31
    int qg = jj & 15;
    int b = bh >> 4, h = bh & 15;
    int qt = qg * 8 + w;               // q-tile (16 rows) owned by this wave

    // ballot bitmask: wave w covers keys w*256 .. w*256+255
    const int* mb = mask + b * 2048;
    #pragma unroll
    for (int i = 0; i < 4; ++i) {
        unsigned long long bal = __ballot(mb[w * 256 + i * 64 + lane] != 0);
        if (lane == 0) maskb[w * 4 + i] = bal;
    }

    const bf16* Qb = Qm + ((size_t)bh * 2048 + (size_t)qt * 16) * 64;
    short8 bQ0 = load8(Qb + l16 * 64 + quad * 8);
    short8 bQ1 = load8(Qb + l16 * 64 + 32 + quad * 8);

    // staging lane constants: each wave stages 8 rows of 128B per async16
    int r8 = lane >> 3, s8 = lane & 7;
    const bf16* Ksrc = Km + (size_t)bh * 131072 + (size_t)(w * 8 + r8) * 64 + ((s8 ^ r8) << 3);
    const bf16* Vsrc = Vt + (size_t)bh * 131072 + (size_t)(w * 8 + r8) * 2048 + ((s8 ^ r8) << 3);

    int sw = l16 & 7;

    float4v zero = {0.f, 0.f, 0.f, 0.f};
    float4v Oacc[4];
    #pragma unroll
    for (int g = 0; g < 4; ++g) Oacc[g] = zero;
    float lsum = 0.f;

    // prologue: stage chunk 0 -> buf0, chunk 1 -> buf1 (2 loads each/wave)
    async16(Ksrc,        (char*)&Kc[0][0] + w * 1024);
    async16(Vsrc,        (char*)&Vc[0][0] + w * 1024);
    async16(Ksrc + 4096, (char*)&Kc[1][0] + w * 1024);
    async16(Vsrc + 64,   (char*)&Vc[1][0] + w * 1024);
    // chunk0 landed (leave chunk1's 2 newest in flight); maskb published
    asm volatile("s_waitcnt vmcnt(2) lgkmcnt(0)" ::: "memory");
    __builtin_amdgcn_s_barrier();
    __builtin_amdgcn_sched_barrier(0);

    int cur = 0, sb = 2;
    for (int it = 0; it < 32; ++it) {
        // issue chunk it+2 into the buffer read two iters ago
        if (it < 30) {
            async16(Ksrc + (size_t)(it + 2) * 4096, (char*)&Kc[sb][0] + w * 1024);
            async16(Vsrc + (size_t)(it + 2) * 64,   (char*)&Vc[sb][0] + w * 1024);
        }

        unsigned long long m64 = maskb[it];
        bool full = (m64 == ~0ull);
        const bf16* Kb = &Kc[cur][0];
        const bf16* Vb = &Vc[cur][0];

        // --- S^T = K Q^T : 4 key-tiles x 1 q-tile ---
        float4v S[4];
        #pragma unroll
        for (int kj = 0; kj < 4; ++kj) {
            const bf16* kr = Kb + (kj * 16 + l16) * 64;
            short8 a0 = load8(kr + (((0 + quad) ^ sw) << 3));
            short8 a1 = load8(kr + (((4 + quad) ^ sw) << 3));
            float4v s = MFMA16(a0, bQ0, zero);
            s = MFMA16(a1, bQ1, s);
            S[kj] = s;
        }

        // --- p = exp2(S) (Q pre-scaled), mask-zero, key-sum, pack ---
        unsigned wlo[4], whi[4];
        #pragma unroll
        for (int kj = 0; kj < 4; ++kj) {
            unsigned m4 = (unsigned)(m64 >> (kj * 16 + quad * 4)) & 0xFu;
            float p[4];
            #pragma unroll
            for (int r = 0; r < 4; ++r)
                p[r] = __builtin_amdgcn_exp2f(S[kj][r]);
            if (!full) {
                #pragma unroll
                for (int r = 0; r < 4; ++r)
                    p[r] = ((m4 >> r) & 1u) ? p[r] : 0.f;
            }
            lsum += (p[0] + p[1]) + (p[2] + p[3]);
            wlo[kj] = pack2(p[0], p[1]);
            whi[kj] = pack2(p[2], p[3]);
        }

        // --- in-register P transpose: quads exchange so dest quad dq holds
        //     keys 32m + 8dq..8dq+7 (same key order as V slots) ---
        short8 ap[2];
        #pragma unroll
        for (int m = 0; m < 2; ++m) {
            uint2v sa = __builtin_amdgcn_permlane32_swap(wlo[2 * m], wlo[2 * m + 1], false, false);
            uint2v qa = __builtin_amdgcn_permlane16_swap(sa[0], sa[1], false, false);
            uint2v sb2 = __builtin_amdgcn_permlane32_swap(whi[2 * m], whi[2 * m + 1], false, false);
            uint2v qb2 = __builtin_amdgcn_permlane16_swap(sb2[0], sb2[1], false, false);
            union { short8 s; unsigned u[4]; } t;
            t.u[0] = qa[0];   // keys 32m+8dq+0,1
            t.u[1] = qb2[0];  // keys 32m+8dq+2,3
            t.u[2] = qa[1];   // keys 32m+8dq+4,5
            t.u[3] = qb2[1];  // keys 32m+8dq+6,7
            ap[m] = t.s;
        }

        // --- O += P V ---
        #pragma unroll
        for (int g = 0; g < 4; ++g) {
            const bf16* vr = Vb + (g * 16 + l16) * 64;
            short8 v0 = load8(vr + (((0 + quad) ^ sw) << 3));
            short8 v1 = load8(vr + (((4 + quad) ^ sw) << 3));
            Oacc[g] = MFMA16(ap[0], v0, Oacc[g]);
            Oacc[g] = MFMA16(ap[1], v1, Oacc[g]);
        }

        // counted wait: chunk it+1 (older) landed, chunk it+2 stays in flight
        if (it < 30) {
            asm volatile("s_waitcnt vmcnt(2)" ::: "memory");
            __builtin_amdgcn_s_barrier();
            __builtin_amdgcn_sched_barrier(0);
        } else if (it == 30) {
            asm volatile("s_waitcnt vmcnt(0)" ::: "memory");
            __builtin_amdgcn_s_barrier();
            __builtin_amdgcn_sched_barrier(0);
        }
        cur = (cur == 2) ? 0 : cur + 1;
        sb  = (sb  == 2) ? 0 : sb + 1;
    }

    float ls = lsum;
    ls += __shfl_xor(ls, 16, 64);
    ls += __shfl_xor(ls, 32, 64);
    #pragma unroll
    for (int r = 0; r < 4; ++r) {
        float linv = 1.f / __shfl(ls, quad * 4 + r, 64);
        int srow = qt * 16 + quad * 4 + r;
        size_t base = ((size_t)b * 2048 + srow) * 1024 + h * 64;
        #pragma unroll
        for (int g = 0; g < 4; ++g)
            Oout[base + g * 16 + l16] = __float2bfloat16(Oacc[g][r] * linv);
    }
}

// ---------------------------------------------------------------------------
// Workspace (16 MB of d_ws; d_out doubles as scratch). 3 launches:
//   ws[0..8):  vb [B,H,Dk,S] bf16 (written by qkv, read by attn)
//   ws[8..16): aout [B,S,1024] bf16 (written by attn, read by out_gemm)
//   d_out[0..8): qb, [8..16): kb (dead before out_gemm overwrites d_out)
//   Weights are consumed fp32 in-kernel (transposed during B staging).
// ---------------------------------------------------------------------------
extern "C" void kernel_launch(void* const* d_in, const int* in_sizes, int n_in,
                              void* d_out, int out_size, void* d_ws, size_t ws_size,
                              hipStream_t stream) {
    const float* query = (const float*)d_in[0];
    const float* key   = (const float*)d_in[1];
    const float* value = (const float*)d_in[2];
    const int*   mask  = (const int*)d_in[3];
    const float* Wq = (const float*)d_in[4];
    const float* bq = (const float*)d_in[5];
    const float* Wk = (const float*)d_in[6];
    const float* bk = (const float*)d_in[7];
    const float* Wv = (const float*)d_in[8];
    const float* bv = (const float*)d_in[9];
    const float* Wo = (const float*)d_in[10];
    const float* bo = (const float*)d_in[11];

    char* ws = (char*)d_ws;
    const size_t MB = 1024 * 1024;
    bf16* vb   = (bf16*)ws;                 // 8 MB
    bf16* aout = (bf16*)(ws + 8 * MB);      // 8 MB
    bf16* qb   = (bf16*)d_out;
    bf16* kb   = (bf16*)((char*)d_out + 8 * MB);
    float* out = (float*)d_out;

    qkv_gemm<<<dim3(768), 256, 0, stream>>>(
        query, key, value, Wq, Wk, Wv, bq, bk, bv, qb, kb, vb);

    attn_fused<<<dim3(512), 512, 0, stream>>>(qb, kb, vb, mask, aout);

    out_gemm<<<dim3(512), 256, 0, stream>>>(aout, Wo, bo, out);
}

// Round 11
// 237.463 us; speedup vs baseline: 1.0408x; 1.0408x over previous
//
#include <hip/hip_runtime.h>
#include <hip/hip_bf16.h>

typedef __attribute__((ext_vector_type(8))) short short8;   // 8 bf16 = 4 VGPRs
typedef __attribute__((ext_vector_type(4))) float float4v;  // 4 fp32 acc
typedef __attribute__((ext_vector_type(2))) unsigned int uint2v;
typedef __hip_bfloat16 bf16;

#define MFMA16(a, b, c) __builtin_amdgcn_mfma_f32_16x16x32_bf16((a), (b), (c), 0, 0, 0)

static __device__ __forceinline__ short8 load8(const bf16* p) {
    return *reinterpret_cast<const short8*>(p);
}
static __device__ __forceinline__ unsigned short bfu(float x) {
    union { bf16 b; unsigned short u; } c; c.b = __float2bfloat16(x); return c.u;
}
static __device__ __forceinline__ unsigned pack2(float lo, float hi) {
    return ((unsigned)bfu(hi) << 16) | bfu(lo);
}
static __device__ __forceinline__ short bf_bits(float x) {
    union { bf16 b; short u; } c; c.b = __float2bfloat16(x); return c.u;
}
static __device__ __forceinline__ short8 cvt8(float4 a, float4 b) {
    short8 r;
    r[0] = bf_bits(a.x); r[1] = bf_bits(a.y); r[2] = bf_bits(a.z); r[3] = bf_bits(a.w);
    r[4] = bf_bits(b.x); r[5] = bf_bits(b.y); r[6] = bf_bits(b.z); r[7] = bf_bits(b.w);
    return r;
}

// async global -> LDS, 16B per lane. LDS dest = wave-uniform base + lane*16.
typedef const __attribute__((address_space(1))) unsigned int* gp1;
typedef __attribute__((address_space(3))) unsigned int* lp3;
static __device__ __forceinline__ void async16(const void* g, void* l) {
    __builtin_amdgcn_global_load_lds((gp1)g, (lp3)l, 16, 0, 0);
}

// ---------------------------------------------------------------------------
// Transpose + convert 1024x1024 fp32 W[k][n] -> bf16 Wt[n][k] for q,k,v.
// (Must precede qkv_gemm -> stays a separate launch. R10 showed in-GEMM
// transpose for qkv costs +21us: W re-read x32 blocks in fp32 + 8-way
// LDS write conflicts. Not worth the ~7us launch gap.)
// ---------------------------------------------------------------------------
__global__ __launch_bounds__(256) void transpose_qkv(
    const float* __restrict__ Wq, const float* __restrict__ Wk,
    const float* __restrict__ Wv, bf16* __restrict__ out_base)
{
    __shared__ bf16 tile[64][65];
    const float* in = (blockIdx.z == 0) ? Wq : (blockIdx.z == 1) ? Wk : Wv;
    bf16* out = out_base + (size_t)blockIdx.z * 1048576;
    int tx = threadIdx.x, ty = threadIdx.y;
    int bx = blockIdx.x * 64, by = blockIdx.y * 64;
    for (int i = ty; i < 64; i += 4)
        tile[i][tx] = __float2bfloat16(in[(size_t)(by + i) * 1024 + bx + tx]);
    __syncthreads();
    for (int i = ty; i < 64; i += 4)
        out[(size_t)(bx + i) * 1024 + by + tx] = tile[tx][i];
}

// ---------------------------------------------------------------------------
// QKV projection GEMM — v3 structure (stable 60-62us) + Q pre-scale:
// q output is multiplied by log2(e)/8 in the epilogue (z==0 only), folding
// the attention score scale into the projection so attn's exp2 argument
// needs no multiply. BK=64, single-buffered, 16 iters, 32 MFMA/barrier-pair.
// ---------------------------------------------------------------------------
__global__ __launch_bounds__(256, 3) void qkv_gemm(
    const float* __restrict__ Xq, const float* __restrict__ Xk,
    const float* __restrict__ Xv, const bf16* __restrict__ Wt_all,
    const float* __restrict__ bq, const float* __restrict__ bk,
    const float* __restrict__ bv,
    bf16* __restrict__ outq, bf16* __restrict__ outk, bf16* __restrict__ outv)
{
    __shared__ float As[128 * 64];   // 32KB
    __shared__ bf16  Bs[128 * 64];   // 16KB

    int wg = blockIdx.x;
    int xcd = wg & 7;
    int jj = wg >> 3;                  // 0..95
    int grp = xcd * 12 + (jj >> 3);    // 0..95
    int z = grp >> 5;                  // 0..2
    int m_blk = grp & 31;
    int n_blk = jj & 7;

    const float* X    = (z == 0) ? Xq : (z == 1) ? Xk : Xv;
    const float* bias = (z == 0) ? bq : (z == 1) ? bk : bv;
    const bf16*  Wt   = Wt_all + (size_t)z * 1048576;
    bf16*        out  = (z == 0) ? outq : (z == 1) ? outk : outv;
    bool vmode = (z == 2);

    int tid = threadIdx.x;
    int w = tid >> 6, lane = tid & 63, l16 = lane & 15, quad = lane >> 4;
    int m_base = m_blk * 128, n_base = n_blk * 128;

    // staging lane constants
    int r4 = lane >> 4, s16 = lane & 15;   // A: 4 rows x 16 slots per async16
    int r8 = lane >> 3, s8 = lane & 7;     // B: 8 rows x  8 slots per async16
    const float* Asrc0 = X + (size_t)(m_base + w * 32 + r4) * 1024 + ((s16 ^ r4) << 2);
    const float* Asrc1 = X + (size_t)(m_base + w * 32 + r4) * 1024 + ((s16 ^ (4 + r4)) << 2);
    const bf16*  Bsrc  = Wt + (size_t)(n_base + w * 32 + r8) * 1024 + ((s8 ^ r8) << 3);

    int wm = (w & 1) * 64, wn = (w >> 1) * 64;
    int sw = l16 & 7;

    float4v zero = {0.f, 0.f, 0.f, 0.f};
    float4v acc[4][4];
    #pragma unroll
    for (int mi = 0; mi < 4; ++mi)
        #pragma unroll
        for (int nj = 0; nj < 4; ++nj) acc[mi][nj] = zero;

    for (int it = 0; it < 16; ++it) {
        int kt = it * 64;
        #pragma unroll
        for (int p = 0; p < 8; ++p) {
            const float* s = ((p & 1) ? Asrc1 : Asrc0) + (size_t)p * 4096 + kt;
            async16(s, (char*)As + (w * 32 + p * 4) * 256);
        }
        #pragma unroll
        for (int p = 0; p < 4; ++p)
            async16(Bsrc + (size_t)p * 8192 + kt, (char*)Bs + (w * 32 + p * 8) * 128);
        __syncthreads();

        #pragma unroll
        for (int kk = 0; kk < 2; ++kk) {
            short8 af[4], bfr[4];
            #pragma unroll
            for (int mi = 0; mi < 4; ++mi) {
                const float* rp = As + (wm + mi * 16 + l16) * 64;
                float4 f0 = *(const float4*)(rp + (((kk * 8 + quad * 2)     ^ sw) << 2));
                float4 f1 = *(const float4*)(rp + (((kk * 8 + quad * 2 + 1) ^ sw) << 2));
                af[mi] = cvt8(f0, f1);
            }
            #pragma unroll
            for (int nj = 0; nj < 4; ++nj) {
                const bf16* rp = Bs + (wn + nj * 16 + l16) * 64;
                bfr[nj] = load8(rp + (((kk * 4 + quad) ^ sw) << 3));
            }
            #pragma unroll
            for (int mi = 0; mi < 4; ++mi)
                #pragma unroll
                for (int nj = 0; nj < 4; ++nj)
                    acc[mi][nj] = MFMA16(af[mi], bfr[nj], acc[mi][nj]);
        }
        __syncthreads();
    }

    float bsv[4];
    #pragma unroll
    for (int nj = 0; nj < 4; ++nj)
        bsv[nj] = bias[n_base + wn + nj * 16 + l16];

    // fold attention scale into q: C = log2(e)/8
    float qs = (z == 0) ? 0.18033688f : 1.0f;

    #pragma unroll
    for (int mi = 0; mi < 4; ++mi) {
        #pragma unroll
        for (int nj = 0; nj < 4; ++nj) {
            int n = n_base + wn + nj * 16 + l16;
            int h = n >> 6, dk = n & 63;
            int m0 = m_base + wm + mi * 16 + quad * 4;
            int b = m0 >> 11, s0 = m0 & 2047;
            if (vmode) {
                float v0 = acc[mi][nj][0] + bsv[nj];
                float v1 = acc[mi][nj][1] + bsv[nj];
                float v2 = acc[mi][nj][2] + bsv[nj];
                float v3 = acc[mi][nj][3] + bsv[nj];
                uint2 pv; pv.x = pack2(v0, v1); pv.y = pack2(v2, v3);
                size_t idx = ((size_t)(b * 16 + h) * 64 + dk) * 2048 + s0;
                *reinterpret_cast<uint2*>(out + idx) = pv;
            } else {
                #pragma unroll
                for (int r = 0; r < 4; ++r) {
                    size_t idx = (((size_t)(b * 16 + h) * 2048 + s0 + r) * 64 + dk);
                    out[idx] = __float2bfloat16((acc[mi][nj][r] + bsv[nj]) * qs);
                }
            }
        }
    }
}

// ---------------------------------------------------------------------------
// Output projection: out[4096,1024] fp32 = A(bf16) @ Wo + bo.
// v7 (validated correct in R10): in-kernel Wo transpose — transpose_one
// kernel + WtO buffer eliminated (5->4 launches). B tile Wo^T[n][k] built
// per-iter from coalesced fp32 row reads of Wo[k][n] (~4-way write
// conflicts; Wo is 4MB, L2/L3-resident so the x32 re-read is cheap).
// Fragment reads unchanged -> bit-identical numerics. BK=128, 8 iters,
// 32 MFMA per barrier-pair. Tile 128x64, grid 512, XCD swizzle.
// ---------------------------------------------------------------------------
__global__ __launch_bounds__(256, 2) void out_gemm(
    const bf16* __restrict__ A, const float* __restrict__ Wo,
    const float* __restrict__ bias, float* __restrict__ out)
{
    __shared__ bf16 As[128 * 128];   // 32KB
    __shared__ bf16 Bs[64 * 128];    // 16KB  [n][k] transposed Wo

    int wg = blockIdx.x;
    int xcd = wg & 7;
    int jj = wg >> 3;                  // 0..63
    int m_blk = xcd * 4 + (jj >> 4);   // 0..31
    int n_blk = jj & 15;

    int tid = threadIdx.x;
    int w = tid >> 6, lane = tid & 63, l16 = lane & 15, quad = lane >> 4;
    int m_base = m_blk * 128, n_base = n_blk * 64;

    // A staging lane constants: each async16 covers 4 rows x 16 slots of 16B
    int r4 = lane >> 4, s16 = lane & 15;

    // B transpose-staging: wave w covers k-rows w*32..w*32+31 as 16 pairs;
    // lane = pair bp (lane>>2) x n-group bli (lane&3).
    int bp  = lane >> 2;               // 0..15 -> rows k0 = w*32 + bp*2, +1
    int bli = lane & 3;                // 0..3  -> n = n_base + bli*16 + i
    const float* Wsrc = Wo + (size_t)(w * 32 + bp * 2) * 1024 + n_base + bli * 16;
    int bslot = w * 4 + (bp >> 2);     // 16B-slot index of k-pair (0..15)
    int bwk   = (bp & 3) * 4;
    char* bbase = (char*)Bs + bli * 4096 + bwk;

    int wm = (w & 1) * 64, wn = (w >> 1) * 32;

    float4v zero = {0.f, 0.f, 0.f, 0.f};
    float4v acc[4][2];
    #pragma unroll
    for (int mi = 0; mi < 4; ++mi)
        #pragma unroll
        for (int nj = 0; nj < 2; ++nj) acc[mi][nj] = zero;

    for (int it = 0; it < 8; ++it) {
        int kt = it * 128;
        // A: wave w stages rows w*32 .. w*32+31 (8 async16 of 4 rows)
        #pragma unroll
        for (int p = 0; p < 8; ++p) {
            int row = w * 32 + p * 4 + r4;
            const bf16* s = A + (size_t)(m_base + row) * 1024 + kt
                              + ((s16 ^ (row & 15)) << 3);
            async16(s, (char*)As + (w * 32 + p * 4) * 256);
        }
        // B: load Wo rows fp32 -> cvt -> transposed swizzled ds_write
        {
            const float* r0 = Wsrc + (size_t)kt * 1024;
            const float* r1 = r0 + 1024;
            float fa[16], fb[16];
            *(float4*)(fa + 0)  = *(const float4*)(r0 + 0);
            *(float4*)(fa + 4)  = *(const float4*)(r0 + 4);
            *(float4*)(fa + 8)  = *(const float4*)(r0 + 8);
            *(float4*)(fa + 12) = *(const float4*)(r0 + 12);
            *(float4*)(fb + 0)  = *(const float4*)(r1 + 0);
            *(float4*)(fb + 4)  = *(const float4*)(r1 + 4);
            *(float4*)(fb + 8)  = *(const float4*)(r1 + 8);
            *(float4*)(fb + 12) = *(const float4*)(r1 + 12);
            #pragma unroll
            for (int i = 0; i < 16; ++i)
                *(unsigned*)(bbase + i * 256 + ((bslot ^ i) << 4)) =
                    pack2(fa[i], fb[i]);
        }
        __syncthreads();

        #pragma unroll
        for (int kk = 0; kk < 4; ++kk) {
            short8 af[4], bfr[2];
            #pragma unroll
            for (int mi = 0; mi < 4; ++mi) {
                const bf16* rp = As + (wm + mi * 16 + l16) * 128;
                af[mi] = load8(rp + (((kk * 4 + quad) ^ l16) << 3));
            }
            #pragma unroll
            for (int nj = 0; nj < 2; ++nj) {
                const bf16* rp = Bs + (wn + nj * 16 + l16) * 128;
                bfr[nj] = load8(rp + (((kk * 4 + quad) ^ l16) << 3));
            }
            #pragma unroll
            for (int mi = 0; mi < 4; ++mi)
                #pragma unroll
                for (int nj = 0; nj < 2; ++nj)
                    acc[mi][nj] = MFMA16(af[mi], bfr[nj], acc[mi][nj]);
        }
        __syncthreads();
    }

    float bsv[2];
    #pragma unroll
    for (int nj = 0; nj < 2; ++nj)
        bsv[nj] = bias[n_base + wn + nj * 16 + l16];

    #pragma unroll
    for (int mi = 0; mi < 4; ++mi)
        #pragma unroll
        for (int nj = 0; nj < 2; ++nj) {
            int n = n_base + wn + nj * 16 + l16;
            int m0 = m_base + wm + mi * 16 + quad * 4;
            #pragma unroll
            for (int r = 0; r < 4; ++r)
                out[(size_t)(m0 + r) * 1024 + n] = acc[mi][nj][r] + bsv[nj];
        }
}

// ---------------------------------------------------------------------------
// Flash attention, S-transposed. v6b (kept; attn plateau ~60us across six
// structural variants): 8 waves x 1 q-tile, grid 512, 3-deep K/V pipeline
// with counted vmcnt + sched_barrier(0) hardening, in-register P via
// permlane swaps, Q pre-scaled by log2(e)/8.
// LDS: 3x8K + 3x8K + maskb = 48.3KB; 2 blocks/CU.
// ---------------------------------------------------------------------------
__global__ __launch_bounds__(512, 4) void attn_fused(
    const bf16* __restrict__ Qm, const bf16* __restrict__ Km,
    const bf16* __restrict__ Vt, const int* __restrict__ mask,
    bf16* __restrict__ Oout)
{
    __shared__ __align__(16) bf16 Kc[3][64 * 64];  // 3 x 8KB [key][d]
    __shared__ __align__(16) bf16 Vc[3][64 * 64];  // 3 x 8KB [d][key]
    __shared__ unsigned long long maskb[32];       // bit k of [c] = mask[c*64+k]

    int tid = threadIdx.x;
    int w = tid >> 6, lane = tid & 63, l16 = lane & 15, quad = lane >> 4;
    int wg = blockIdx.x;
    int xcd = wg & 7;
    int jj = wg >> 3;                  // 0..63
    int bh = xcd * 4 + (jj >> 4);      // 0..31
    int qg = jj & 15;
    int b = bh >> 4, h = bh & 15;
    int qt = qg * 8 + w;               // q-tile (16 rows) owned by this wave

    // ballot bitmask: wave w covers keys w*256 .. w*256+255
    const int* mb = mask + b * 2048;
    #pragma unroll
    for (int i = 0; i < 4; ++i) {
        unsigned long long bal = __ballot(mb[w * 256 + i * 64 + lane] != 0);
        if (lane == 0) maskb[w * 4 + i] = bal;
    }

    const bf16* Qb = Qm + ((size_t)bh * 2048 + (size_t)qt * 16) * 64;
    short8 bQ0 = load8(Qb + l16 * 64 + quad * 8);
    short8 bQ1 = load8(Qb + l16 * 64 + 32 + quad * 8);

    // staging lane constants: each wave stages 8 rows of 128B per async16
    int r8 = lane >> 3, s8 = lane & 7;
    const bf16* Ksrc = Km + (size_t)bh * 131072 + (size_t)(w * 8 + r8) * 64 + ((s8 ^ r8) << 3);
    const bf16* Vsrc = Vt + (size_t)bh * 131072 + (size_t)(w * 8 + r8) * 2048 + ((s8 ^ r8) << 3);

    int sw = l16 & 7;

    float4v zero = {0.f, 0.f, 0.f, 0.f};
    float4v Oacc[4];
    #pragma unroll
    for (int g = 0; g < 4; ++g) Oacc[g] = zero;
    float lsum = 0.f;

    // prologue: stage chunk 0 -> buf0, chunk 1 -> buf1 (2 loads each/wave)
    async16(Ksrc,        (char*)&Kc[0][0] + w * 1024);
    async16(Vsrc,        (char*)&Vc[0][0] + w * 1024);
    async16(Ksrc + 4096, (char*)&Kc[1][0] + w * 1024);
    async16(Vsrc + 64,   (char*)&Vc[1][0] + w * 1024);
    // chunk0 landed (leave chunk1's 2 newest in flight); maskb published
    asm volatile("s_waitcnt vmcnt(2) lgkmcnt(0)" ::: "memory");
    __builtin_amdgcn_s_barrier();
    __builtin_amdgcn_sched_barrier(0);

    int cur = 0, sb = 2;
    for (int it = 0; it < 32; ++it) {
        // issue chunk it+2 into the buffer read two iters ago
        if (it < 30) {
            async16(Ksrc + (size_t)(it + 2) * 4096, (char*)&Kc[sb][0] + w * 1024);
            async16(Vsrc + (size_t)(it + 2) * 64,   (char*)&Vc[sb][0] + w * 1024);
        }

        unsigned long long m64 = maskb[it];
        bool full = (m64 == ~0ull);
        const bf16* Kb = &Kc[cur][0];
        const bf16* Vb = &Vc[cur][0];

        // --- S^T = K Q^T : 4 key-tiles x 1 q-tile ---
        float4v S[4];
        #pragma unroll
        for (int kj = 0; kj < 4; ++kj) {
            const bf16* kr = Kb + (kj * 16 + l16) * 64;
            short8 a0 = load8(kr + (((0 + quad) ^ sw) << 3));
            short8 a1 = load8(kr + (((4 + quad) ^ sw) << 3));
            float4v s = MFMA16(a0, bQ0, zero);
            s = MFMA16(a1, bQ1, s);
            S[kj] = s;
        }

        // --- p = exp2(S) (Q pre-scaled), mask-zero, key-sum, pack ---
        unsigned wlo[4], whi[4];
        #pragma unroll
        for (int kj = 0; kj < 4; ++kj) {
            unsigned m4 = (unsigned)(m64 >> (kj * 16 + quad * 4)) & 0xFu;
            float p[4];
            #pragma unroll
            for (int r = 0; r < 4; ++r)
                p[r] = __builtin_amdgcn_exp2f(S[kj][r]);
            if (!full) {
                #pragma unroll
                for (int r = 0; r < 4; ++r)
                    p[r] = ((m4 >> r) & 1u) ? p[r] : 0.f;
            }
            lsum += (p[0] + p[1]) + (p[2] + p[3]);
            wlo[kj] = pack2(p[0], p[1]);
            whi[kj] = pack2(p[2], p[3]);
        }

        // --- in-register P transpose: quads exchange so dest quad dq holds
        //     keys 32m + 8dq..8dq+7 (same key order as V slots) ---
        short8 ap[2];
        #pragma unroll
        for (int m = 0; m < 2; ++m) {
            uint2v sa = __builtin_amdgcn_permlane32_swap(wlo[2 * m], wlo[2 * m + 1], false, false);
            uint2v qa = __builtin_amdgcn_permlane16_swap(sa[0], sa[1], false, false);
            uint2v sb2 = __builtin_amdgcn_permlane32_swap(whi[2 * m], whi[2 * m + 1], false, false);
            uint2v qb2 = __builtin_amdgcn_permlane16_swap(sb2[0], sb2[1], false, false);
            union { short8 s; unsigned u[4]; } t;
            t.u[0] = qa[0];   // keys 32m+8dq+0,1
            t.u[1] = qb2[0];  // keys 32m+8dq+2,3
            t.u[2] = qa[1];   // keys 32m+8dq+4,5
            t.u[3] = qb2[1];  // keys 32m+8dq+6,7
            ap[m] = t.s;
        }

        // --- O += P V ---
        #pragma unroll
        for (int g = 0; g < 4; ++g) {
            const bf16* vr = Vb + (g * 16 + l16) * 64;
            short8 v0 = load8(vr + (((0 + quad) ^ sw) << 3));
            short8 v1 = load8(vr + (((4 + quad) ^ sw) << 3));
            Oacc[g] = MFMA16(ap[0], v0, Oacc[g]);
            Oacc[g] = MFMA16(ap[1], v1, Oacc[g]);
        }

        // counted wait: chunk it+1 (older) landed, chunk it+2 stays in flight
        if (it < 30) {
            asm volatile("s_waitcnt vmcnt(2)" ::: "memory");
            __builtin_amdgcn_s_barrier();
            __builtin_amdgcn_sched_barrier(0);
        } else if (it == 30) {
            asm volatile("s_waitcnt vmcnt(0)" ::: "memory");
            __builtin_amdgcn_s_barrier();
            __builtin_amdgcn_sched_barrier(0);
        }
        cur = (cur == 2) ? 0 : cur + 1;
        sb  = (sb  == 2) ? 0 : sb + 1;
    }

    float ls = lsum;
    ls += __shfl_xor(ls, 16, 64);
    ls += __shfl_xor(ls, 32, 64);
    #pragma unroll
    for (int r = 0; r < 4; ++r) {
        float linv = 1.f / __shfl(ls, quad * 4 + r, 64);
        int srow = qt * 16 + quad * 4 + r;
        size_t base = ((size_t)b * 2048 + srow) * 1024 + h * 64;
        #pragma unroll
        for (int g = 0; g < 4; ++g)
            Oout[base + g * 16 + l16] = __float2bfloat16(Oacc[g][r] * linv);
    }
}

// ---------------------------------------------------------------------------
// Workspace (16 MB of d_ws; d_out doubles as scratch). 4 launches:
//   ws[ 0.. 8): vb [B,H,Dk,S] bf16 (qkv -> attn)
//   ws[ 8..14): Wq^T,Wk^T,Wv^T bf16 (transpose_qkv -> qkv, then dead)
//   ws[ 8..16): aout [B,S,1024] bf16 (attn -> out_gemm, over dead Wt_all)
//   d_out[0..8): qb, [8..16): kb (dead before out_gemm overwrites d_out)
//   Wo consumed fp32 directly by out_gemm (in-kernel transpose; no WtO).
// ---------------------------------------------------------------------------
extern "C" void kernel_launch(void* const* d_in, const int* in_sizes, int n_in,
                              void* d_out, int out_size, void* d_ws, size_t ws_size,
                              hipStream_t stream) {
    const float* query = (const float*)d_in[0];
    const float* key   = (const float*)d_in[1];
    const float* value = (const float*)d_in[2];
    const int*   mask  = (const int*)d_in[3];
    const float* Wq = (const float*)d_in[4];
    const float* bq = (const float*)d_in[5];
    const float* Wk = (const float*)d_in[6];
    const float* bk = (const float*)d_in[7];
    const float* Wv = (const float*)d_in[8];
    const float* bv = (const float*)d_in[9];
    const float* Wo = (const float*)d_in[10];
    const float* bo = (const float*)d_in[11];

    char* ws = (char*)d_ws;
    const size_t MB = 1024 * 1024;
    bf16* vb     = (bf16*)ws;                 // 8 MB
    bf16* Wt_all = (bf16*)(ws + 8 * MB);      // 3 x 2 MB (dead after qkv)
    bf16* aout   = (bf16*)(ws + 8 * MB);      // 8 MB (over dead Wt_all)
    bf16* qb     = (bf16*)d_out;
    bf16* kb     = (bf16*)((char*)d_out + 8 * MB);
    float* out   = (float*)d_out;

    transpose_qkv<<<dim3(16, 16, 3), dim3(64, 4), 0, stream>>>(Wq, Wk, Wv, Wt_all);

    qkv_gemm<<<dim3(768), 256, 0, stream>>>(
        query, key, value, Wt_all, bq, bk, bv, qb, kb, vb);

    attn_fused<<<dim3(512), 512, 0, stream>>>(qb, kb, vb, mask, aout);

    out_gemm<<<dim3(512), 256, 0, stream>>>(aout, Wo, bo, out);
}